// Round 2
// baseline (307.461 us; speedup 1.0000x reference)
//
#include <hip/hip_runtime.h>

// Problem constants (match reference)
#define NC 128
#define NS 2048
#define NX 256
#define NZ 512
#define NB 4                 // B*K
#define NROWS (NX * NZ)      // 131072 output pixels
#define NCOLS (NS * NC)      // 262144 rhs rows

// NOTE: harness passes ALL integer inputs as int32 (csr_rows/csr_cols arrive
// as int*, not int64* — reading them as long long OOB-faults: 134MB from 67MB).

// Kernel 1: pack x (B,K,NC,NS) into rhs[j] = float4 over batch, j = s*NC + c.
// rhs[s*128+c][b] = x[b*NC*NS + c*NS + s]
__global__ void pack_rhs_kernel(const float* __restrict__ x,
                                float4* __restrict__ rhs) {
    int j = blockIdx.x * blockDim.x + threadIdx.x;
    if (j >= NCOLS) return;
    int c = j & (NC - 1);
    int s = j >> 7;
    int base = c * NS + s;
    float4 v;
    v.x = x[base];
    v.y = x[base + 1 * NC * NS];
    v.z = x[base + 2 * NC * NS];
    v.w = x[base + 3 * NC * NS];
    rhs[j] = v;
}

// Kernel 2: segment boundaries via binary search on sorted int32 rows.
// row_start[r] = lower_bound(rows, r), r in [0, NROWS].
__global__ void row_bounds_kernel(const int* __restrict__ rows, int nnz,
                                  int* __restrict__ row_start) {
    int r = blockIdx.x * blockDim.x + threadIdx.x;
    if (r > NROWS) return;
    int lo = 0, hi = nnz;
    while (lo < hi) {
        int mid = (lo + hi) >> 1;
        if (rows[mid] < r) lo = mid + 1;
        else hi = mid;
    }
    row_start[r] = lo;
}

// Kernel 3: one wave (64 lanes) per output row; atomic-free.
__global__ void __launch_bounds__(256) spmm_kernel(
        const float* __restrict__ vals,
        const int* __restrict__ cols,
        const int* __restrict__ row_start,
        const float4* __restrict__ rhs,
        float* __restrict__ out) {
    int r = (blockIdx.x << 2) + (threadIdx.x >> 6);   // wave id == row
    int lane = threadIdx.x & 63;
    int start = row_start[r];
    int end   = row_start[r + 1];

    float4 acc = {0.f, 0.f, 0.f, 0.f};
    for (int i = start + lane; i < end; i += 64) {
        float v = vals[i];             // coalesced 4B/lane
        int col = cols[i];             // coalesced 4B/lane
        float4 rv = rhs[col];          // random 16B gather, L2/L3-resident
        acc.x += v * rv.x;
        acc.y += v * rv.y;
        acc.z += v * rv.z;
        acc.w += v * rv.w;
    }

    // 64-lane butterfly reduction of float4
    #pragma unroll
    for (int off = 32; off >= 1; off >>= 1) {
        acc.x += __shfl_xor(acc.x, off, 64);
        acc.y += __shfl_xor(acc.y, off, 64);
        acc.z += __shfl_xor(acc.z, off, 64);
        acc.w += __shfl_xor(acc.w, off, 64);
    }

    if (lane < 4) {
        float o = (lane == 0) ? acc.x : (lane == 1) ? acc.y
                : (lane == 2) ? acc.z : acc.w;
        int ix = r >> 9;          // r / NZ
        int iz = r & (NZ - 1);    // r % NZ
        // out[b, iz, ix] = img_vec[ix*NZ+iz, b]
        out[lane * NROWS + iz * NX + ix] = o;
    }
}

// Fallback (no workspace): inline row-bound search + direct gather from x.
__global__ void __launch_bounds__(256) spmm_direct_kernel(
        const float* __restrict__ x,
        const float* __restrict__ vals,
        const int* __restrict__ rows,
        const int* __restrict__ cols,
        int nnz,
        float* __restrict__ out) {
    int r = (blockIdx.x << 2) + (threadIdx.x >> 6);
    int lane = threadIdx.x & 63;

    // lower_bound(r) and lower_bound(r+1); wave-uniform, cached probes
    int start, end;
    {
        int lo = 0, hi = nnz;
        while (lo < hi) { int mid = (lo + hi) >> 1; if (rows[mid] < r) lo = mid + 1; else hi = mid; }
        start = lo;
        hi = nnz;
        int key = r + 1;
        while (lo < hi) { int mid = (lo + hi) >> 1; if (rows[mid] < key) lo = mid + 1; else hi = mid; }
        end = lo;
    }

    float4 acc = {0.f, 0.f, 0.f, 0.f};
    for (int i = start + lane; i < end; i += 64) {
        float v = vals[i];
        int col = cols[i];
        int c = col & (NC - 1);
        int s = col >> 7;
        int base = c * NS + s;
        acc.x += v * x[base];
        acc.y += v * x[base + 1 * NC * NS];
        acc.z += v * x[base + 2 * NC * NS];
        acc.w += v * x[base + 3 * NC * NS];
    }

    #pragma unroll
    for (int off = 32; off >= 1; off >>= 1) {
        acc.x += __shfl_xor(acc.x, off, 64);
        acc.y += __shfl_xor(acc.y, off, 64);
        acc.z += __shfl_xor(acc.z, off, 64);
        acc.w += __shfl_xor(acc.w, off, 64);
    }

    if (lane < 4) {
        float o = (lane == 0) ? acc.x : (lane == 1) ? acc.y
                : (lane == 2) ? acc.z : acc.w;
        int ix = r >> 9;
        int iz = r & (NZ - 1);
        out[lane * NROWS + iz * NX + ix] = o;
    }
}

extern "C" void kernel_launch(void* const* d_in, const int* in_sizes, int n_in,
                              void* d_out, int out_size, void* d_ws, size_t ws_size,
                              hipStream_t stream) {
    const float* x        = (const float*)d_in[0];
    const float* csr_vals = (const float*)d_in[1];
    const int*   csr_rows = (const int*)d_in[2];   // harness passes integers as int32
    const int*   csr_cols = (const int*)d_in[3];
    float* out = (float*)d_out;
    int nnz = in_sizes[1];

    size_t need = (size_t)NCOLS * sizeof(float4) + (size_t)(NROWS + 1) * sizeof(int);
    if (ws_size >= need) {
        float4* rhs       = (float4*)d_ws;
        int*    row_start = (int*)((char*)d_ws + (size_t)NCOLS * sizeof(float4));
        pack_rhs_kernel<<<(NCOLS + 255) / 256, 256, 0, stream>>>(x, rhs);
        row_bounds_kernel<<<(NROWS + 1 + 255) / 256, 256, 0, stream>>>(csr_rows, nnz, row_start);
        spmm_kernel<<<NROWS / 4, 256, 0, stream>>>(csr_vals, csr_cols, row_start, rhs, out);
    } else {
        spmm_direct_kernel<<<NROWS / 4, 256, 0, stream>>>(x, csr_vals, csr_rows, csr_cols, nnz, out);
    }
}